// Round 3
// baseline (7521.278 us; speedup 1.0000x reference)
//
#include <hip/hip_runtime.h>
#include <math.h>

// Problem constants: B=4, S=2048, HID=512, NH=8, DH=64
#define S_LEN 2048
#define HIDDIM 512
#define NHEAD 8
#define DHEAD 64
#define NBH 32      // B*NH
#define MTOT 8192   // B*S

typedef _Float16 half4 __attribute__((ext_vector_type(4)));

// HW transcendentals: v_exp_f32 = 2^x, v_log_f32 = log2(x).
__device__ __forceinline__ float fast_exp2(float x) { return __builtin_amdgcn_exp2f(x); }
__device__ __forceinline__ float fast_log2(float x) { return __builtin_amdgcn_logf(x); }
// max(x,0)^pinv via exp2(log2(x)*pinv); log2(0)=-inf -> exp2(-inf)=0 handles the clip.
__device__ __forceinline__ float powclip(float x, float pinv) {
    return fast_exp2(fast_log2(fmaxf(x, 0.f)) * pinv);
}

// ---------------------------------------------------------------------------
// f32 GEMM: out = X @ W^T + bias.
//   mode 0: out[m*512 + n]                 mode 1: out[bh][s][d]
//   mode 2: out[bh][d][s]  (transposed, for Kt and Vt)
// ---------------------------------------------------------------------------
__global__ __launch_bounds__(256) void gemm_xwt(
    const float* __restrict__ X, const float* __restrict__ W,
    const float* __restrict__ bias, float* __restrict__ out,
    int mode, float scale)
{
    __shared__ float Xs[16][68];
    __shared__ float Ws[16][68];

    const int m0 = blockIdx.x * 64;
    const int n0 = blockIdx.y * 64;
    const int t  = threadIdx.x;
    const int tx = t & 15;
    const int ty = t >> 4;
    const int lrow = t >> 2;
    const int lk0  = (t & 3) << 2;

    float acc[4][4];
#pragma unroll
    for (int i = 0; i < 4; ++i)
#pragma unroll
        for (int j = 0; j < 4; ++j) acc[i][j] = 0.f;

    for (int kt = 0; kt < HIDDIM; kt += 16) {
        float4 xv = *(const float4*)&X[(size_t)(m0 + lrow) * HIDDIM + kt + lk0];
        float4 wv = *(const float4*)&W[(size_t)(n0 + lrow) * HIDDIM + kt + lk0];
        __syncthreads();
        Xs[lk0 + 0][lrow] = xv.x; Xs[lk0 + 1][lrow] = xv.y;
        Xs[lk0 + 2][lrow] = xv.z; Xs[lk0 + 3][lrow] = xv.w;
        Ws[lk0 + 0][lrow] = wv.x; Ws[lk0 + 1][lrow] = wv.y;
        Ws[lk0 + 2][lrow] = wv.z; Ws[lk0 + 3][lrow] = wv.w;
        __syncthreads();
#pragma unroll
        for (int kk = 0; kk < 16; ++kk) {
            float4 a = *(const float4*)&Xs[kk][ty << 2];
            float4 b = *(const float4*)&Ws[kk][tx << 2];
            float av[4] = {a.x, a.y, a.z, a.w};
            float bv[4] = {b.x, b.y, b.z, b.w};
#pragma unroll
            for (int i = 0; i < 4; ++i)
#pragma unroll
                for (int j = 0; j < 4; ++j) acc[i][j] += av[i] * bv[j];
        }
    }

#pragma unroll
    for (int i = 0; i < 4; ++i) {
        const int m  = m0 + (ty << 2) + i;
        const int bb = m >> 11;
        const int ss = m & 2047;
#pragma unroll
        for (int j = 0; j < 4; ++j) {
            const int n = n0 + (tx << 2) + j;
            const float v = (acc[i][j] + bias[n]) * scale;
            size_t idx;
            if (mode == 0) {
                idx = (size_t)m * HIDDIM + n;
            } else {
                const int h = n >> 6, d = n & 63;
                if (mode == 1)
                    idx = ((size_t)(bb * NHEAD + h) * S_LEN + ss) * DHEAD + d;
                else
                    idx = ((size_t)(bb * NHEAD + h) * DHEAD + d) * S_LEN + ss;
            }
            out[idx] = v;
        }
    }
}

// ---------------------------------------------------------------------------
// Fused entmax-1.33 attention.
// Grid: 32 bh * 128 q-tiles = 4096 blocks, 512 threads (8 waves), 16 q-rows.
// Each wave owns 2 query rows; lane tc holds k = kb*256 + tc*4 + c in sc[2][32].
// Bisection (22 iters, f_lo>=0 always so test is sum>=1) fully in registers.
// Probs -> fp16 LDS; PV reads transposed V (wave d-slices, V read once/block).
// ---------------------------------------------------------------------------
__global__ __launch_bounds__(512, 3) void attn_entmax(
    const float* __restrict__ Q,   // [32][2048][64], pre-scaled by (a-1)/sqrt(DH)
    const float* __restrict__ Kt,  // [32][64][2048]
    const float* __restrict__ Vt,  // [32][64][2048]
    float* __restrict__ CTX,       // [8192][512]
    float pinv, float dm0)
{
    __shared__ float Qs[16][64];
    __shared__ _Float16 P[16][2052]; // stride 2052h=1026dw => rows hit distinct banks
    __shared__ float rowsum[16];

    const int bh = blockIdx.x >> 7;
    const int q0 = (blockIdx.x & 127) << 4;
    const int t  = threadIdx.x;

    if (t < 256) {   // load 16x64 Q tile
        const int r = t >> 4;
        const int d = (t & 15) << 2;
        *(float4*)&Qs[r][d] =
            *(const float4*)&Q[((size_t)bh * S_LEN + q0 + r) * DHEAD + d];
    }
    __syncthreads();

    const int w  = t >> 6;     // wave 0..7, rows 2w..2w+1
    const int tc = t & 63;
    const int r0 = w << 1;

    float sc[2][32];
#pragma unroll
    for (int i = 0; i < 2; ++i)
#pragma unroll
        for (int j = 0; j < 32; ++j) sc[i][j] = 0.f;

    const float* KtB = Kt + (size_t)bh * DHEAD * S_LEN;

    // ---- Phase A: scores (Xa) into registers -----------------------------
#pragma unroll
    for (int kb = 0; kb < 8; ++kb) {
        const int kbase = (kb << 8) + (tc << 2);
        for (int dc = 0; dc < 16; ++dc) {
            const float* kp = KtB + (size_t)(dc << 2) * S_LEN + kbase;
            float4 k0 = *(const float4*)(kp);
            float4 k1 = *(const float4*)(kp + S_LEN);
            float4 k2 = *(const float4*)(kp + 2 * S_LEN);
            float4 k3 = *(const float4*)(kp + 3 * S_LEN);
#pragma unroll
            for (int i = 0; i < 2; ++i) {
                float4 q = *(const float4*)&Qs[r0 + i][dc << 2];
                sc[i][(kb << 2) + 0] += q.x * k0.x + q.y * k1.x + q.z * k2.x + q.w * k3.x;
                sc[i][(kb << 2) + 1] += q.x * k0.y + q.y * k1.y + q.z * k2.y + q.w * k3.y;
                sc[i][(kb << 2) + 2] += q.x * k0.z + q.y * k1.z + q.z * k2.z + q.w * k3.z;
                sc[i][(kb << 2) + 3] += q.x * k0.w + q.y * k1.w + q.z * k2.w + q.w * k3.w;
            }
        }
    }

    // ---- Phase B: entmax bisection -------------------------------------
    // f_lo = sum(clip(Xa-(max-1))^inv)-1 >= 1-1 = 0 always (max elem gives 1),
    // so the reference's f_m*f_lo>=0 test == (sum_m >= 1). No f_lo pass needed.
    float tau[2];
#pragma unroll
    for (int i = 0; i < 2; ++i) {
        float m = sc[i][0];
#pragma unroll
        for (int j = 1; j < 32; ++j) m = fmaxf(m, sc[i][j]);
#pragma unroll
        for (int o = 32; o > 0; o >>= 1) m = fmaxf(m, __shfl_xor(m, o, 64));
        tau[i] = m - 1.0f;
    }
    float dm = dm0;
    // 22 iters: |tau err| <= dm0*2^-22 ~ 2e-7 -> |p err| <= 7e-7 (== 50-iter ref)
    for (int it = 0; it < 22; ++it) {
        dm *= 0.5f;
        const float t0 = tau[0] + dm, t1 = tau[1] + dm;
        float s0 = 0.f, s1 = 0.f;
#pragma unroll
        for (int j = 0; j < 32; ++j) {
            s0 += powclip(sc[0][j] - t0, pinv);
            s1 += powclip(sc[1][j] - t1, pinv);
        }
#pragma unroll
        for (int o = 32; o > 0; o >>= 1) {
            s0 += __shfl_xor(s0, o, 64);
            s1 += __shfl_xor(s1, o, 64);
        }
        if (s0 >= 1.0f) tau[0] = t0;
        if (s1 >= 1.0f) tau[1] = t1;
    }

    // ---- Phase C: final probs -> fp16 LDS, row sums ----------------------
#pragma unroll
    for (int i = 0; i < 2; ++i) {
        float s = 0.f;
#pragma unroll
        for (int kb = 0; kb < 8; ++kb) {
            half4 hv;
#pragma unroll
            for (int c = 0; c < 4; ++c) {
                float p = powclip(sc[i][(kb << 2) + c] - tau[i], pinv);
                s += p;
                hv[c] = (_Float16)p;
            }
            *(half4*)&P[r0 + i][(kb << 8) + (tc << 2)] = hv;
        }
#pragma unroll
        for (int o = 32; o > 0; o >>= 1) s += __shfl_xor(s, o, 64);
        if (tc == 0) rowsum[r0 + i] = s;
    }
    __syncthreads();

    // ---- Phase D: PV with transposed V -----------------------------------
    // wave w owns d-slice [8w, 8w+8); lane: row = l>>2 (16 rows x 4 lanes),
    // d = 8w + (l&3)*2. V read exactly once per block.
    const int l   = t & 63;
    const int row = l >> 2;
    const int d   = (w << 3) + ((l & 3) << 1);
    const float* v0 = Vt + ((size_t)bh * DHEAD + d) * S_LEN;
    const float* v1 = v0 + S_LEN;
    float a0 = 0.f, a1 = 0.f;
    for (int k = 0; k < S_LEN; k += 4) {
        half4 ph = *(const half4*)&P[row][k];
        float4 x0 = *(const float4*)&v0[k];
        float4 x1 = *(const float4*)&v1[k];
        const float p0 = (float)ph[0], p1 = (float)ph[1];
        const float p2 = (float)ph[2], p3 = (float)ph[3];
        a0 += p0 * x0.x + p1 * x0.y + p2 * x0.z + p3 * x0.w;
        a1 += p0 * x1.x + p1 * x1.y + p2 * x1.z + p3 * x1.w;
    }
    const float rsc = 1.0f / rowsum[row];
    const int b = bh >> 3, h = bh & 7;
    float2 o = make_float2(a0 * rsc, a1 * rsc);
    *(float2*)&CTX[((size_t)b * S_LEN + q0 + row) * HIDDIM + (h << 6) + d] = o;
}

// ---------------------------------------------------------------------------
extern "C" void kernel_launch(void* const* d_in, const int* in_sizes, int n_in,
                              void* d_out, int out_size, void* d_ws, size_t ws_size,
                              hipStream_t stream)
{
    const float* hs = (const float*)d_in[0];
    const float* Wq = (const float*)d_in[1];
    const float* bq = (const float*)d_in[2];
    const float* Wk = (const float*)d_in[3];
    const float* bk = (const float*)d_in[4];
    const float* Wv = (const float*)d_in[5];
    const float* bv = (const float*)d_in[6];
    const float* Wo = (const float*)d_in[7];
    const float* bo = (const float*)d_in[8];
    float* out = (float*)d_out;

    const size_t per = (size_t)NBH * S_LEN * DHEAD;
    float* Qb  = (float*)d_ws;
    float* Ktb = Qb  + per;
    float* Vtb = Ktb + per;
    float* CTX = Vtb + per;

    const double am1d  = 1.33 - 1.0;
    const float qscale = (float)(am1d / 8.0);          // fold (a-1)/sqrt(DH) into Q
    const float pinv   = (float)(1.0 / am1d);
    const float dm0    = (float)(1.0 - exp2(-11.0 * am1d)); // 1-(1/2048)^(a-1)

    dim3 gp(MTOT / 64, HIDDIM / 64);
    gemm_xwt<<<gp, 256, 0, stream>>>(hs, Wq, bq, Qb,  1, qscale);
    gemm_xwt<<<gp, 256, 0, stream>>>(hs, Wk, bk, Ktb, 2, 1.0f);
    gemm_xwt<<<gp, 256, 0, stream>>>(hs, Wv, bv, Vtb, 2, 1.0f);
    attn_entmax<<<dim3(NBH * (S_LEN / 16)), 512, 0, stream>>>(Qb, Ktb, Vtb, CTX, pinv, dm0);
    gemm_xwt<<<gp, 256, 0, stream>>>(CTX, Wo, bo, out, 0, 1.0f);
}

// Round 4
// 6158.499 us; speedup vs baseline: 1.2213x; 1.2213x over previous
//
#include <hip/hip_runtime.h>
#include <math.h>

// Problem constants: B=4, S=2048, HID=512, NH=8, DH=64
#define S_LEN 2048
#define HIDDIM 512
#define NHEAD 8
#define DHEAD 64
#define NBH 32      // B*NH
#define MTOT 8192   // B*S

typedef _Float16 half4 __attribute__((ext_vector_type(4)));

// HW transcendentals: v_exp_f32 = 2^x, v_log_f32 = log2(x).
__device__ __forceinline__ float fast_exp2(float x) { return __builtin_amdgcn_exp2f(x); }
__device__ __forceinline__ float fast_log2(float x) { return __builtin_amdgcn_logf(x); }
// max(x,0)^pinv via exp2(log2(x)*pinv); log2(0)=-inf -> exp2(-inf)=0 handles the clip.
__device__ __forceinline__ float powclip(float x, float pinv) {
    return fast_exp2(fast_log2(fmaxf(x, 0.f)) * pinv);
}

// ---------------------------------------------------------------------------
// f32 GEMM: out = X @ W^T + bias.
//   mode 0: out[m*512 + n]                 mode 1: out[bh][s][d]
//   mode 2: out[bh][d][s]  (transposed, for Kt and Vt)
// ---------------------------------------------------------------------------
__global__ __launch_bounds__(256) void gemm_xwt(
    const float* __restrict__ X, const float* __restrict__ W,
    const float* __restrict__ bias, float* __restrict__ out,
    int mode, float scale)
{
    __shared__ float Xs[16][68];
    __shared__ float Ws[16][68];

    const int m0 = blockIdx.x * 64;
    const int n0 = blockIdx.y * 64;
    const int t  = threadIdx.x;
    const int tx = t & 15;
    const int ty = t >> 4;
    const int lrow = t >> 2;
    const int lk0  = (t & 3) << 2;

    float acc[4][4];
#pragma unroll
    for (int i = 0; i < 4; ++i)
#pragma unroll
        for (int j = 0; j < 4; ++j) acc[i][j] = 0.f;

    for (int kt = 0; kt < HIDDIM; kt += 16) {
        float4 xv = *(const float4*)&X[(size_t)(m0 + lrow) * HIDDIM + kt + lk0];
        float4 wv = *(const float4*)&W[(size_t)(n0 + lrow) * HIDDIM + kt + lk0];
        __syncthreads();
        Xs[lk0 + 0][lrow] = xv.x; Xs[lk0 + 1][lrow] = xv.y;
        Xs[lk0 + 2][lrow] = xv.z; Xs[lk0 + 3][lrow] = xv.w;
        Ws[lk0 + 0][lrow] = wv.x; Ws[lk0 + 1][lrow] = wv.y;
        Ws[lk0 + 2][lrow] = wv.z; Ws[lk0 + 3][lrow] = wv.w;
        __syncthreads();
#pragma unroll
        for (int kk = 0; kk < 16; ++kk) {
            float4 a = *(const float4*)&Xs[kk][ty << 2];
            float4 b = *(const float4*)&Ws[kk][tx << 2];
            float av[4] = {a.x, a.y, a.z, a.w};
            float bv[4] = {b.x, b.y, b.z, b.w};
#pragma unroll
            for (int i = 0; i < 4; ++i)
#pragma unroll
                for (int j = 0; j < 4; ++j) acc[i][j] += av[i] * bv[j];
        }
    }

#pragma unroll
    for (int i = 0; i < 4; ++i) {
        const int m  = m0 + (ty << 2) + i;
        const int bb = m >> 11;
        const int ss = m & 2047;
#pragma unroll
        for (int j = 0; j < 4; ++j) {
            const int n = n0 + (tx << 2) + j;
            const float v = (acc[i][j] + bias[n]) * scale;
            size_t idx;
            if (mode == 0) {
                idx = (size_t)m * HIDDIM + n;
            } else {
                const int h = n >> 6, d = n & 63;
                if (mode == 1)
                    idx = ((size_t)(bb * NHEAD + h) * S_LEN + ss) * DHEAD + d;
                else
                    idx = ((size_t)(bb * NHEAD + h) * DHEAD + d) * S_LEN + ss;
            }
            out[idx] = v;
        }
    }
}

// ---------------------------------------------------------------------------
// Fused entmax-1.33 attention.
// Grid: 4096 blocks, 512 threads (8 waves), 16 q-rows per block.
// XCD-aware swizzle: blocks land on XCD (bid&7); give XCD x the bh range
// [4x, 4x+4) so all resident blocks on an XCD share one bh's K/V (1 MB -> L2).
// Each wave owns 2 query rows; lane tc holds k = kb*256 + tc*4 + c in sc[2][32].
// Bisection (22 iters; f_lo >= 0 always so the test is sum >= 1) in registers.
// Probs -> fp16 LDS; PV reads transposed V (wave d-slices, V read once/block).
// ---------------------------------------------------------------------------
__global__ __launch_bounds__(512) void attn_entmax(
    const float* __restrict__ Q,   // [32][2048][64], pre-scaled by (a-1)/sqrt(DH)
    const float* __restrict__ Kt,  // [32][64][2048]
    const float* __restrict__ Vt,  // [32][64][2048]
    float* __restrict__ CTX,       // [8192][512]
    float pinv, float dm0)
{
    __shared__ float Qs[16][64];
    __shared__ _Float16 P[16][2052]; // row stride 1026 dw -> rows hit distinct banks
    __shared__ float rowsum[16];

    const int bid = blockIdx.x;
    const int bh  = ((bid & 7) << 2) + (bid >> 10);   // XCD-local bh
    const int q0  = ((bid >> 3) & 127) << 4;
    const int t   = threadIdx.x;

    if (t < 256) {   // load 16x64 Q tile
        const int r = t >> 4;
        const int d = (t & 15) << 2;
        *(float4*)&Qs[r][d] =
            *(const float4*)&Q[((size_t)bh * S_LEN + q0 + r) * DHEAD + d];
    }
    __syncthreads();

    const int w  = t >> 6;     // wave 0..7, rows 2w..2w+1
    const int tc = t & 63;
    const int r0 = w << 1;

    float sc[2][32];
#pragma unroll
    for (int i = 0; i < 2; ++i)
#pragma unroll
        for (int j = 0; j < 32; ++j) sc[i][j] = 0.f;

    const float* KtB = Kt + (size_t)bh * DHEAD * S_LEN;

    // ---- Phase A: scores (Xa) into registers -----------------------------
#pragma unroll
    for (int kb = 0; kb < 8; ++kb) {
        const int kbase = (kb << 8) + (tc << 2);
        for (int dc = 0; dc < 16; ++dc) {
            const float* kp = KtB + (size_t)(dc << 2) * S_LEN + kbase;
            float4 k0 = *(const float4*)(kp);
            float4 k1 = *(const float4*)(kp + S_LEN);
            float4 k2 = *(const float4*)(kp + 2 * S_LEN);
            float4 k3 = *(const float4*)(kp + 3 * S_LEN);
#pragma unroll
            for (int i = 0; i < 2; ++i) {
                float4 q = *(const float4*)&Qs[r0 + i][dc << 2];
                sc[i][(kb << 2) + 0] += q.x * k0.x + q.y * k1.x + q.z * k2.x + q.w * k3.x;
                sc[i][(kb << 2) + 1] += q.x * k0.y + q.y * k1.y + q.z * k2.y + q.w * k3.y;
                sc[i][(kb << 2) + 2] += q.x * k0.z + q.y * k1.z + q.z * k2.z + q.w * k3.z;
                sc[i][(kb << 2) + 3] += q.x * k0.w + q.y * k1.w + q.z * k2.w + q.w * k3.w;
            }
        }
    }

    // ---- Phase B: entmax bisection -------------------------------------
    // f_lo = sum(clip(Xa-(max-1))^inv)-1 >= 1-1 = 0 always (max elem gives 1),
    // so the reference's f_m*f_lo>=0 test == (sum_m >= 1). No f_lo pass needed.
    float tau[2];
#pragma unroll
    for (int i = 0; i < 2; ++i) {
        float m = sc[i][0];
#pragma unroll
        for (int j = 1; j < 32; ++j) m = fmaxf(m, sc[i][j]);
#pragma unroll
        for (int o = 32; o > 0; o >>= 1) m = fmaxf(m, __shfl_xor(m, o, 64));
        tau[i] = m - 1.0f;
    }
    float dm = dm0;
    // 22 iters: |tau err| <= dm0*2^-22 ~ 2e-7 -> |p err| <= 7e-7 (== 50-iter ref)
    for (int it = 0; it < 22; ++it) {
        dm *= 0.5f;
        const float t0 = tau[0] + dm, t1 = tau[1] + dm;
        float s0 = 0.f, s1 = 0.f;
#pragma unroll
        for (int j = 0; j < 32; ++j) {
            s0 += powclip(sc[0][j] - t0, pinv);
            s1 += powclip(sc[1][j] - t1, pinv);
        }
#pragma unroll
        for (int o = 32; o > 0; o >>= 1) {
            s0 += __shfl_xor(s0, o, 64);
            s1 += __shfl_xor(s1, o, 64);
        }
        if (s0 >= 1.0f) tau[0] = t0;
        if (s1 >= 1.0f) tau[1] = t1;
    }

    // ---- Phase C: final probs -> fp16 LDS, row sums ----------------------
#pragma unroll
    for (int i = 0; i < 2; ++i) {
        float s = 0.f;
#pragma unroll
        for (int kb = 0; kb < 8; ++kb) {
            half4 hv;
#pragma unroll
            for (int c = 0; c < 4; ++c) {
                float p = powclip(sc[i][(kb << 2) + c] - tau[i], pinv);
                s += p;
                hv[c] = (_Float16)p;
            }
            *(half4*)&P[r0 + i][(kb << 8) + (tc << 2)] = hv;
        }
#pragma unroll
        for (int o = 32; o > 0; o >>= 1) s += __shfl_xor(s, o, 64);
        if (tc == 0) rowsum[r0 + i] = s;
    }
    __syncthreads();

    // ---- Phase D: PV with transposed V -----------------------------------
    // wave w owns d-slice [8w, 8w+8); lane: row = l>>2 (16 rows x 4 lanes),
    // d = 8w + (l&3)*2. V read exactly once per block.
    const int l   = t & 63;
    const int row = l >> 2;
    const int d   = (w << 3) + ((l & 3) << 1);
    const float* v0 = Vt + ((size_t)bh * DHEAD + d) * S_LEN;
    const float* v1 = v0 + S_LEN;
    float a0 = 0.f, a1 = 0.f;
    for (int k = 0; k < S_LEN; k += 4) {
        half4 ph = *(const half4*)&P[row][k];
        float4 x0 = *(const float4*)&v0[k];
        float4 x1 = *(const float4*)&v1[k];
        const float p0 = (float)ph[0], p1 = (float)ph[1];
        const float p2 = (float)ph[2], p3 = (float)ph[3];
        a0 += p0 * x0.x + p1 * x0.y + p2 * x0.z + p3 * x0.w;
        a1 += p0 * x1.x + p1 * x1.y + p2 * x1.z + p3 * x1.w;
    }
    const float rsc = 1.0f / rowsum[row];
    const int b = bh >> 3, h = bh & 7;
    float2 o = make_float2(a0 * rsc, a1 * rsc);
    *(float2*)&CTX[((size_t)b * S_LEN + q0 + row) * HIDDIM + (h << 6) + d] = o;
}

// ---------------------------------------------------------------------------
extern "C" void kernel_launch(void* const* d_in, const int* in_sizes, int n_in,
                              void* d_out, int out_size, void* d_ws, size_t ws_size,
                              hipStream_t stream)
{
    const float* hs = (const float*)d_in[0];
    const float* Wq = (const float*)d_in[1];
    const float* bq = (const float*)d_in[2];
    const float* Wk = (const float*)d_in[3];
    const float* bk = (const float*)d_in[4];
    const float* Wv = (const float*)d_in[5];
    const float* bv = (const float*)d_in[6];
    const float* Wo = (const float*)d_in[7];
    const float* bo = (const float*)d_in[8];
    float* out = (float*)d_out;

    const size_t per = (size_t)NBH * S_LEN * DHEAD;
    float* Qb  = (float*)d_ws;
    float* Ktb = Qb  + per;
    float* Vtb = Ktb + per;
    float* CTX = Vtb + per;

    const double am1d  = 1.33 - 1.0;
    const float qscale = (float)(am1d / 8.0);          // fold (a-1)/sqrt(DH) into Q
    const float pinv   = (float)(1.0 / am1d);
    const float dm0    = (float)(1.0 - exp2(-11.0 * am1d)); // 1-(1/2048)^(a-1)

    dim3 gp(MTOT / 64, HIDDIM / 64);
    gemm_xwt<<<gp, 256, 0, stream>>>(hs, Wq, bq, Qb,  1, qscale);
    gemm_xwt<<<gp, 256, 0, stream>>>(hs, Wk, bk, Ktb, 2, 1.0f);
    gemm_xwt<<<gp, 256, 0, stream>>>(hs, Wv, bv, Vtb, 2, 1.0f);
    attn_entmax<<<dim3(NBH * (S_LEN / 16)), 512, 0, stream>>>(Qb, Ktb, Vtb, CTX, pinv, dm0);
    gemm_xwt<<<gp, 256, 0, stream>>>(CTX, Wo, bo, out, 0, 1.0f);
}

// Round 5
// 5969.629 us; speedup vs baseline: 1.2599x; 1.0316x over previous
//
#include <hip/hip_runtime.h>
#include <math.h>

// Problem constants: B=4, S=2048, HID=512, NH=8, DH=64
#define S_LEN 2048
#define HIDDIM 512
#define NHEAD 8
#define DHEAD 64
#define NBH 32      // B*NH
#define MTOT 8192   // B*S

typedef _Float16 half2v __attribute__((ext_vector_type(2)));
typedef _Float16 half4 __attribute__((ext_vector_type(4)));

// HW transcendentals: v_exp_f32 = 2^x, v_log_f32 = log2(x).
__device__ __forceinline__ float fast_exp2(float x) { return __builtin_amdgcn_exp2f(x); }
__device__ __forceinline__ float fast_log2(float x) { return __builtin_amdgcn_logf(x); }
// max(x,0)^pinv via exp2(log2(x)*pinv); log2(0)=-inf -> exp2(-inf)=0 handles the clip.
__device__ __forceinline__ float powclip(float x, float pinv) {
    return fast_exp2(fast_log2(fmaxf(x, 0.f)) * pinv);
}

// ---------------------------------------------------------------------------
// f32 GEMM: out = X @ W^T + bias.
//   mode 0: out[m*512 + n]                 mode 1: out[bh][s][d]
//   mode 2: out[bh][d][s]  (transposed, for Kt and Vt)
// ---------------------------------------------------------------------------
__global__ __launch_bounds__(256) void gemm_xwt(
    const float* __restrict__ X, const float* __restrict__ W,
    const float* __restrict__ bias, float* __restrict__ out,
    int mode, float scale)
{
    __shared__ float Xs[16][68];
    __shared__ float Ws[16][68];

    const int m0 = blockIdx.x * 64;
    const int n0 = blockIdx.y * 64;
    const int t  = threadIdx.x;
    const int tx = t & 15;
    const int ty = t >> 4;
    const int lrow = t >> 2;
    const int lk0  = (t & 3) << 2;

    float acc[4][4];
#pragma unroll
    for (int i = 0; i < 4; ++i)
#pragma unroll
        for (int j = 0; j < 4; ++j) acc[i][j] = 0.f;

    for (int kt = 0; kt < HIDDIM; kt += 16) {
        float4 xv = *(const float4*)&X[(size_t)(m0 + lrow) * HIDDIM + kt + lk0];
        float4 wv = *(const float4*)&W[(size_t)(n0 + lrow) * HIDDIM + kt + lk0];
        __syncthreads();
        Xs[lk0 + 0][lrow] = xv.x; Xs[lk0 + 1][lrow] = xv.y;
        Xs[lk0 + 2][lrow] = xv.z; Xs[lk0 + 3][lrow] = xv.w;
        Ws[lk0 + 0][lrow] = wv.x; Ws[lk0 + 1][lrow] = wv.y;
        Ws[lk0 + 2][lrow] = wv.z; Ws[lk0 + 3][lrow] = wv.w;
        __syncthreads();
#pragma unroll
        for (int kk = 0; kk < 16; ++kk) {
            float4 a = *(const float4*)&Xs[kk][ty << 2];
            float4 b = *(const float4*)&Ws[kk][tx << 2];
            float av[4] = {a.x, a.y, a.z, a.w};
            float bv[4] = {b.x, b.y, b.z, b.w};
#pragma unroll
            for (int i = 0; i < 4; ++i)
#pragma unroll
                for (int j = 0; j < 4; ++j) acc[i][j] += av[i] * bv[j];
        }
    }

#pragma unroll
    for (int i = 0; i < 4; ++i) {
        const int m  = m0 + (ty << 2) + i;
        const int bb = m >> 11;
        const int ss = m & 2047;
#pragma unroll
        for (int j = 0; j < 4; ++j) {
            const int n = n0 + (tx << 2) + j;
            const float v = (acc[i][j] + bias[n]) * scale;
            size_t idx;
            if (mode == 0) {
                idx = (size_t)m * HIDDIM + n;
            } else {
                const int h = n >> 6, d = n & 63;
                if (mode == 1)
                    idx = ((size_t)(bb * NHEAD + h) * S_LEN + ss) * DHEAD + d;
                else
                    idx = ((size_t)(bb * NHEAD + h) * DHEAD + d) * S_LEN + ss;
            }
            out[idx] = v;
        }
    }
}

// ---------------------------------------------------------------------------
// Fused entmax-1.33 attention, k-sliced mapping.
// Grid 4096 blocks x 1024 threads (16 waves). Block owns (bh, 16 q-rows).
// Wave w owns k-slice [128w,128w+128); lane tc owns k-pair kbase=128w+2tc and
// holds ALL 16 rows in sc0[16]/sc1[16]  ->  K read ONCE per block (coalesced
// float2), Q broadcast from LDS. 32 VGPRs of score state; no spill.
// Row sums need block-level reduction: 64-lane butterfly per row, then
// cross-wave via red[16][16]; wave 0 owns authoritative tauLDS[16].
// XCD swizzle: XCD x gets bh in [4x,4x+4) so K+V (1 MB) stays L2-resident.
// ---------------------------------------------------------------------------
__global__ __launch_bounds__(1024) void attn_entmax(
    const float* __restrict__ Q,   // [32][2048][64], pre-scaled by (a-1)/sqrt(DH)
    const float* __restrict__ Kt,  // [32][64][2048]
    const float* __restrict__ Vt,  // [32][64][2048]
    float* __restrict__ CTX,       // [8192][512]
    float pinv, float dm0)
{
    __shared__ float Qs[16][64];
    __shared__ _Float16 P[16][2052]; // row stride 2052h: rows land on distinct banks
    __shared__ float red[16][16];    // [wave][row] partial sums
    __shared__ float tauLDS[16];
    __shared__ float rowsum[16];

    const int bid = blockIdx.x;
    const int bh  = ((bid & 7) << 2) + (bid >> 10);   // XCD-local bh
    const int q0  = ((bid >> 3) & 127) << 4;
    const int t   = threadIdx.x;
    const int w   = t >> 6;     // wave 0..15: k-slice owner
    const int tc  = t & 63;

    if (t < 256) {   // load 16x64 Q tile
        const int r = t >> 4;
        const int d = (t & 15) << 2;
        *(float4*)&Qs[r][d] =
            *(const float4*)&Q[((size_t)bh * S_LEN + q0 + r) * DHEAD + d];
    }
    __syncthreads();

    // ---- Phase A: scores. lane: k-pair kbase, all 16 rows ----------------
    const int kbase = (w << 7) + (tc << 1);
    float sc0[16], sc1[16];
#pragma unroll
    for (int r = 0; r < 16; ++r) { sc0[r] = 0.f; sc1[r] = 0.f; }

    const float* kp = Kt + (size_t)bh * DHEAD * S_LEN + kbase;
    for (int d = 0; d < DHEAD; d += 2) {
        const float2 ka = *(const float2*)(kp);
        const float2 kb = *(const float2*)(kp + S_LEN);
        kp += 2 * S_LEN;
#pragma unroll
        for (int r = 0; r < 16; ++r) {
            const float2 q = *(const float2*)&Qs[r][d];   // wave-uniform broadcast
            sc0[r] += q.x * ka.x + q.y * kb.x;
            sc1[r] += q.x * ka.y + q.y * kb.y;
        }
    }

    // ---- max pass -> tauLDS = rowmax - 1 ---------------------------------
    {
        float m[16];
#pragma unroll
        for (int r = 0; r < 16; ++r) {
            float v = fmaxf(sc0[r], sc1[r]);
#pragma unroll
            for (int o = 1; o < 64; o <<= 1) v = fmaxf(v, __shfl_xor(v, o, 64));
            m[r] = v;
        }
        if (tc == 0) {
#pragma unroll
            for (int r = 0; r < 16; ++r) red[w][r] = m[r];
        }
        __syncthreads();
        if (w == 0 && tc < 16) {
            float mm = red[0][tc];
#pragma unroll
            for (int w2 = 1; w2 < 16; ++w2) mm = fmaxf(mm, red[w2][tc]);
            tauLDS[tc] = mm - 1.0f;
        }
        __syncthreads();
    }

    float tau[16];
#pragma unroll
    for (int r = 0; r < 16; ++r) tau[r] = tauLDS[r];

    // ---- bisection: 22 iters (f_lo >= 0 always => test is sum >= 1) ------
    float dm = dm0;
    for (int it = 0; it < 22; ++it) {
        dm *= 0.5f;
        float part[16];
#pragma unroll
        for (int r = 0; r < 16; ++r) {
            const float tm = tau[r] + dm;
            part[r] = powclip(sc0[r] - tm, pinv) + powclip(sc1[r] - tm, pinv);
        }
#pragma unroll
        for (int r = 0; r < 16; ++r) {
            float v = part[r];
#pragma unroll
            for (int o = 1; o < 64; o <<= 1) v += __shfl_xor(v, o, 64);
            part[r] = v;
        }
        if (tc == 0) {
#pragma unroll
            for (int r = 0; r < 16; ++r) red[w][r] = part[r];
        }
        __syncthreads();
        if (w == 0 && tc < 16) {
            float s = red[0][tc];
#pragma unroll
            for (int w2 = 1; w2 < 16; ++w2) s += red[w2][tc];
            if (s >= 1.0f) tauLDS[tc] += dm;
        }
        __syncthreads();
#pragma unroll
        for (int r = 0; r < 16; ++r) tau[r] = tauLDS[r];
    }

    // ---- Phase C: final probs -> fp16 LDS, row sums ----------------------
    {
        float part[16];
#pragma unroll
        for (int r = 0; r < 16; ++r) {
            const float p0 = powclip(sc0[r] - tau[r], pinv);
            const float p1 = powclip(sc1[r] - tau[r], pinv);
            part[r] = p0 + p1;
            half2v hv; hv[0] = (_Float16)p0; hv[1] = (_Float16)p1;
            *(half2v*)&P[r][kbase] = hv;
        }
#pragma unroll
        for (int r = 0; r < 16; ++r) {
            float v = part[r];
#pragma unroll
            for (int o = 1; o < 64; o <<= 1) v += __shfl_xor(v, o, 64);
            part[r] = v;
        }
        if (tc == 0) {
#pragma unroll
            for (int r = 0; r < 16; ++r) red[w][r] = part[r];
        }
        __syncthreads();
        if (w == 0 && tc < 16) {
            float s = red[0][tc];
#pragma unroll
            for (int w2 = 1; w2 < 16; ++w2) s += red[w2][tc];
            rowsum[tc] = s;
        }
        __syncthreads();
    }

    // ---- Phase D: PV. wave w owns d in {4w..4w+3}; lane: (row, d) --------
    const int row = tc >> 2;
    const int d   = (w << 2) + (tc & 3);
    const float* vp = Vt + ((size_t)bh * DHEAD + d) * S_LEN;
    float acc = 0.f;
    for (int k = 0; k < S_LEN; k += 4) {
        half4 ph = *(const half4*)&P[row][k];
        float4 v = *(const float4*)&vp[k];
        acc += (float)ph[0] * v.x + (float)ph[1] * v.y
             + (float)ph[2] * v.z + (float)ph[3] * v.w;
    }
    acc *= 1.0f / rowsum[row];
    const int b = bh >> 3, h = bh & 7;
    CTX[((size_t)b * S_LEN + q0 + row) * HIDDIM + (h << 6) + d] = acc;
}

// ---------------------------------------------------------------------------
extern "C" void kernel_launch(void* const* d_in, const int* in_sizes, int n_in,
                              void* d_out, int out_size, void* d_ws, size_t ws_size,
                              hipStream_t stream)
{
    const float* hs = (const float*)d_in[0];
    const float* Wq = (const float*)d_in[1];
    const float* bq = (const float*)d_in[2];
    const float* Wk = (const float*)d_in[3];
    const float* bk = (const float*)d_in[4];
    const float* Wv = (const float*)d_in[5];
    const float* bv = (const float*)d_in[6];
    const float* Wo = (const float*)d_in[7];
    const float* bo = (const float*)d_in[8];
    float* out = (float*)d_out;

    const size_t per = (size_t)NBH * S_LEN * DHEAD;
    float* Qb  = (float*)d_ws;
    float* Ktb = Qb  + per;
    float* Vtb = Ktb + per;
    float* CTX = Vtb + per;

    const double am1d  = 1.33 - 1.0;
    const float qscale = (float)(am1d / 8.0);          // fold (a-1)/sqrt(DH) into Q
    const float pinv   = (float)(1.0 / am1d);
    const float dm0    = (float)(1.0 - exp2(-11.0 * am1d)); // 1-(1/2048)^(a-1)

    dim3 gp(MTOT / 64, HIDDIM / 64);
    gemm_xwt<<<gp, 256, 0, stream>>>(hs, Wq, bq, Qb,  1, qscale);
    gemm_xwt<<<gp, 256, 0, stream>>>(hs, Wk, bk, Ktb, 2, 1.0f);
    gemm_xwt<<<gp, 256, 0, stream>>>(hs, Wv, bv, Vtb, 2, 1.0f);
    attn_entmax<<<dim3(NBH * (S_LEN / 16)), 1024, 0, stream>>>(Qb, Ktb, Vtb, CTX, pinv, dm0);
    gemm_xwt<<<gp, 256, 0, stream>>>(CTX, Wo, bo, out, 0, 1.0f);
}

// Round 6
// 4771.302 us; speedup vs baseline: 1.5764x; 1.2512x over previous
//
#include <hip/hip_runtime.h>
#include <math.h>

// Problem constants: B=4, S=2048, HID=512, NH=8, DH=64
#define S_LEN 2048
#define HIDDIM 512
#define NHEAD 8
#define DHEAD 64
#define NBH 32      // B*NH
#define MTOT 8192   // B*S

// HW transcendentals: v_exp_f32 = 2^x, v_log_f32 = log2(x).
__device__ __forceinline__ float fast_exp2(float x) { return __builtin_amdgcn_exp2f(x); }
__device__ __forceinline__ float fast_log2(float x) { return __builtin_amdgcn_logf(x); }
// max(x,0)^pinv via exp2(log2(x)*pinv); log2(0)=-inf -> exp2(-inf)=0 handles the clip.
__device__ __forceinline__ float powclip(float x, float pinv) {
    return fast_exp2(fast_log2(fmaxf(x, 0.f)) * pinv);
}

// ---------------------------------------------------------------------------
// f32 GEMM: out = X @ W^T + bias.
//   mode 0: out[m*512 + n]                 mode 1: out[bh][s][d]
//   mode 2: out[bh][d][s]  (transposed, for Kt and Vt)
// ---------------------------------------------------------------------------
__global__ __launch_bounds__(256) void gemm_xwt(
    const float* __restrict__ X, const float* __restrict__ W,
    const float* __restrict__ bias, float* __restrict__ out,
    int mode, float scale)
{
    __shared__ float Xs[16][68];
    __shared__ float Ws[16][68];

    const int m0 = blockIdx.x * 64;
    const int n0 = blockIdx.y * 64;
    const int t  = threadIdx.x;
    const int tx = t & 15;
    const int ty = t >> 4;
    const int lrow = t >> 2;
    const int lk0  = (t & 3) << 2;

    float acc[4][4];
#pragma unroll
    for (int i = 0; i < 4; ++i)
#pragma unroll
        for (int j = 0; j < 4; ++j) acc[i][j] = 0.f;

    for (int kt = 0; kt < HIDDIM; kt += 16) {
        float4 xv = *(const float4*)&X[(size_t)(m0 + lrow) * HIDDIM + kt + lk0];
        float4 wv = *(const float4*)&W[(size_t)(n0 + lrow) * HIDDIM + kt + lk0];
        __syncthreads();
        Xs[lk0 + 0][lrow] = xv.x; Xs[lk0 + 1][lrow] = xv.y;
        Xs[lk0 + 2][lrow] = xv.z; Xs[lk0 + 3][lrow] = xv.w;
        Ws[lk0 + 0][lrow] = wv.x; Ws[lk0 + 1][lrow] = wv.y;
        Ws[lk0 + 2][lrow] = wv.z; Ws[lk0 + 3][lrow] = wv.w;
        __syncthreads();
#pragma unroll
        for (int kk = 0; kk < 16; ++kk) {
            float4 a = *(const float4*)&Xs[kk][ty << 2];
            float4 b = *(const float4*)&Ws[kk][tx << 2];
            float av[4] = {a.x, a.y, a.z, a.w};
            float bv[4] = {b.x, b.y, b.z, b.w};
#pragma unroll
            for (int i = 0; i < 4; ++i)
#pragma unroll
                for (int j = 0; j < 4; ++j) acc[i][j] += av[i] * bv[j];
        }
    }

#pragma unroll
    for (int i = 0; i < 4; ++i) {
        const int m  = m0 + (ty << 2) + i;
        const int bb = m >> 11;
        const int ss = m & 2047;
#pragma unroll
        for (int j = 0; j < 4; ++j) {
            const int n = n0 + (tx << 2) + j;
            const float v = (acc[i][j] + bias[n]) * scale;
            size_t idx;
            if (mode == 0) {
                idx = (size_t)m * HIDDIM + n;
            } else {
                const int h = n >> 6, d = n & 63;
                if (mode == 1)
                    idx = ((size_t)(bb * NHEAD + h) * S_LEN + ss) * DHEAD + d;
                else
                    idx = ((size_t)(bb * NHEAD + h) * DHEAD + d) * S_LEN + ss;
            }
            out[idx] = v;
        }
    }
}

// ---------------------------------------------------------------------------
// Fused entmax-1.33 attention.
// Grid 4096 blocks x 1024 threads (16 waves). Block owns (bh, 16 q-rows).
// Phase A (k-sliced, K read ONCE per block): wave w owns k-slice
//   [128w,128w+128), lane tc owns k-pair kbase=128w+2tc, all 16 rows in regs.
//   Scores (Xa) written to fp32 LDS S[16][2052].
// Phase B (row-owning, barrier-free): wave w owns row w; lane holds 32 elems
//   in regs. 22 bisection iters, each = 64 transcendentals + one 6-step
//   __shfl_xor butterfly. No __syncthreads in the loop (this was round 5's
//   serialization: 96 shuffles + 2 block barriers + 16-thread serial segment
//   per iteration).
// Phase D: wave w owns d in {4w..4w+3}; V (transposed) read once per block.
// XCD swizzle: XCD x gets bh in [4x,4x+4) so K+V (1 MB) stays L2-resident.
// ---------------------------------------------------------------------------
__global__ __launch_bounds__(1024) void attn_entmax(
    const float* __restrict__ Q,   // [32][2048][64], pre-scaled by (a-1)/sqrt(DH)
    const float* __restrict__ Kt,  // [32][64][2048]
    const float* __restrict__ Vt,  // [32][64][2048]
    float* __restrict__ CTX,       // [8192][512]
    float pinv, float dm0)
{
    __shared__ float S[16][2052];   // fp32 scores -> probs (131.3 KB)
    __shared__ float Qs[16][64];
    __shared__ float rowsum[16];

    const int bid = blockIdx.x;
    const int bh  = ((bid & 7) << 2) + (bid >> 10);   // XCD-local bh
    const int q0  = ((bid >> 3) & 127) << 4;
    const int t   = threadIdx.x;
    const int w   = t >> 6;     // wave 0..15
    const int tc  = t & 63;

    if (t < 256) {   // load 16x64 Q tile
        const int r = t >> 4;
        const int d = (t & 15) << 2;
        *(float4*)&Qs[r][d] =
            *(const float4*)&Q[((size_t)bh * S_LEN + q0 + r) * DHEAD + d];
    }
    __syncthreads();

    // ---- Phase A: scores. wave w: k-slice; lane: k-pair, all 16 rows -----
    {
        const int kbase = (w << 7) + (tc << 1);
        float sc0[16], sc1[16];
#pragma unroll
        for (int r = 0; r < 16; ++r) { sc0[r] = 0.f; sc1[r] = 0.f; }

        const float* kp = Kt + (size_t)bh * DHEAD * S_LEN + kbase;
        for (int d = 0; d < DHEAD; d += 2) {
            const float2 ka = *(const float2*)(kp);
            const float2 kb = *(const float2*)(kp + S_LEN);
            kp += 2 * S_LEN;
#pragma unroll
            for (int r = 0; r < 16; ++r) {
                const float2 q = *(const float2*)&Qs[r][d];   // wave-uniform broadcast
                sc0[r] += q.x * ka.x + q.y * kb.x;
                sc1[r] += q.x * ka.y + q.y * kb.y;
            }
        }
#pragma unroll
        for (int r = 0; r < 16; ++r)
            *(float2*)&S[r][kbase] = make_float2(sc0[r], sc1[r]);
    }
    __syncthreads();

    // ---- Phase B: per-wave bisection. wave w owns row w. -----------------
    {
        float sc[32];
#pragma unroll
        for (int j = 0; j < 8; ++j) {
            float4 v = *(const float4*)&S[w][(j << 8) + (tc << 2)];
            sc[4 * j + 0] = v.x; sc[4 * j + 1] = v.y;
            sc[4 * j + 2] = v.z; sc[4 * j + 3] = v.w;
        }

        // row max -> tau = max - 1
        float m = sc[0];
#pragma unroll
        for (int j = 1; j < 32; ++j) m = fmaxf(m, sc[j]);
#pragma unroll
        for (int o = 1; o < 64; o <<= 1) m = fmaxf(m, __shfl_xor(m, o, 64));
        float tau = m - 1.0f;

        // f_lo = sum(clip(Xa-(max-1))^inv)-1 >= 0 always (max elem alone = 1),
        // so reference's f_m*f_lo>=0 test == (sum_m >= 1). 22 iters: tau err
        // <= dm0*2^-22 ~ 2e-7 -> p err <= 7e-7 (matches 50-iter reference).
        float dm = dm0;
        for (int it = 0; it < 22; ++it) {
            dm *= 0.5f;
            const float tm = tau + dm;
            float s = 0.f;
#pragma unroll
            for (int j = 0; j < 32; ++j) s += powclip(sc[j] - tm, pinv);
#pragma unroll
            for (int o = 1; o < 64; o <<= 1) s += __shfl_xor(s, o, 64);
            if (s >= 1.0f) tau = tm;
        }

        // final probs back to LDS (fp32), row sum
        float s = 0.f;
#pragma unroll
        for (int j = 0; j < 8; ++j) {
            float4 p4;
            p4.x = powclip(sc[4 * j + 0] - tau, pinv);
            p4.y = powclip(sc[4 * j + 1] - tau, pinv);
            p4.z = powclip(sc[4 * j + 2] - tau, pinv);
            p4.w = powclip(sc[4 * j + 3] - tau, pinv);
            s += p4.x + p4.y + p4.z + p4.w;
            *(float4*)&S[w][(j << 8) + (tc << 2)] = p4;
        }
#pragma unroll
        for (int o = 1; o < 64; o <<= 1) s += __shfl_xor(s, o, 64);
        if (tc == 0) rowsum[w] = s;
    }
    __syncthreads();

    // ---- Phase D: PV. wave w owns d in {4w..4w+3}; lane: (row, d) --------
    const int row = tc >> 2;
    const int d   = (w << 2) + (tc & 3);
    const float* vp = Vt + ((size_t)bh * DHEAD + d) * S_LEN;
    float acc = 0.f;
    for (int k = 0; k < S_LEN; k += 4) {
        float4 p4 = *(const float4*)&S[row][k];
        float4 v  = *(const float4*)&vp[k];
        acc += p4.x * v.x + p4.y * v.y + p4.z * v.z + p4.w * v.w;
    }
    acc *= 1.0f / rowsum[row];
    const int b = bh >> 3, h = bh & 7;
    CTX[((size_t)b * S_LEN + q0 + row) * HIDDIM + (h << 6) + d] = acc;
}

// ---------------------------------------------------------------------------
extern "C" void kernel_launch(void* const* d_in, const int* in_sizes, int n_in,
                              void* d_out, int out_size, void* d_ws, size_t ws_size,
                              hipStream_t stream)
{
    const float* hs = (const float*)d_in[0];
    const float* Wq = (const float*)d_in[1];
    const float* bq = (const float*)d_in[2];
    const float* Wk = (const float*)d_in[3];
    const float* bk = (const float*)d_in[4];
    const float* Wv = (const float*)d_in[5];
    const float* bv = (const float*)d_in[6];
    const float* Wo = (const float*)d_in[7];
    const float* bo = (const float*)d_in[8];
    float* out = (float*)d_out;

    const size_t per = (size_t)NBH * S_LEN * DHEAD;
    float* Qb  = (float*)d_ws;
    float* Ktb = Qb  + per;
    float* Vtb = Ktb + per;
    float* CTX = Vtb + per;

    const double am1d  = 1.33 - 1.0;
    const float qscale = (float)(am1d / 8.0);          // fold (a-1)/sqrt(DH) into Q
    const float pinv   = (float)(1.0 / am1d);
    const float dm0    = (float)(1.0 - exp2(-11.0 * am1d)); // 1-(1/2048)^(a-1)

    dim3 gp(MTOT / 64, HIDDIM / 64);
    gemm_xwt<<<gp, 256, 0, stream>>>(hs, Wq, bq, Qb,  1, qscale);
    gemm_xwt<<<gp, 256, 0, stream>>>(hs, Wk, bk, Ktb, 2, 1.0f);
    gemm_xwt<<<gp, 256, 0, stream>>>(hs, Wv, bv, Vtb, 2, 1.0f);
    attn_entmax<<<dim3(NBH * (S_LEN / 16)), 1024, 0, stream>>>(Qb, Ktb, Vtb, CTX, pinv, dm0);
    gemm_xwt<<<gp, 256, 0, stream>>>(CTX, Wo, bo, out, 0, 1.0f);
}

// Round 8
// 4615.204 us; speedup vs baseline: 1.6297x; 1.0338x over previous
//
#include <hip/hip_runtime.h>
#include <math.h>

// Problem constants: B=4, S=2048, HID=512, NH=8, DH=64
#define S_LEN 2048
#define HIDDIM 512
#define NHEAD 8
#define DHEAD 64
#define NBH 32      // B*NH
#define MTOT 8192   // B*S

// HW transcendentals: v_log_f32 = log2(x), v_rcp_f32.
__device__ __forceinline__ float fast_log2(float x) { return __builtin_amdgcn_logf(x); }
__device__ __forceinline__ float fast_rcp(float x)  { return __builtin_amdgcn_rcpf(x); }

// p = u^pinv = u^3 * u^(pinv-3);  u^(pinv-3) = e^z, z = (pinv-3)*ln2*log2(u).
// For mass-carrying u (>=1e-4) |z| <= 0.28 -> cubic Taylor rel err <= 2.6e-4;
// for tiny u the u^3 factor kills the poly error (u=1e-30 clamp: u^3
// underflows to 0, 0*poly = -0.0, harmless). ONE trans op per element
// instead of log2+exp2.
__device__ __forceinline__ float upow(float u, float zc) {
    const float z    = zc * fast_log2(u);
    const float poly = 1.f + z * (1.f + z * (0.5f + z * 0.166666667f));
    return u * u * u * poly;
}

// ---------------------------------------------------------------------------
// f32 GEMM: out = X @ W^T + bias.
//   mode 0: out[m*512 + n]                 mode 1: out[bh][s][d]
//   mode 2: out[bh][d][s]  (transposed, for Kt and Vt)
// ---------------------------------------------------------------------------
__global__ __launch_bounds__(256) void gemm_xwt(
    const float* __restrict__ X, const float* __restrict__ W,
    const float* __restrict__ bias, float* __restrict__ out,
    int mode, float scale)
{
    __shared__ float Xs[16][68];
    __shared__ float Ws[16][68];

    const int m0 = blockIdx.x * 64;
    const int n0 = blockIdx.y * 64;
    const int t  = threadIdx.x;
    const int tx = t & 15;
    const int ty = t >> 4;
    const int lrow = t >> 2;
    const int lk0  = (t & 3) << 2;

    float acc[4][4];
#pragma unroll
    for (int i = 0; i < 4; ++i)
#pragma unroll
        for (int j = 0; j < 4; ++j) acc[i][j] = 0.f;

    for (int kt = 0; kt < HIDDIM; kt += 16) {
        float4 xv = *(const float4*)&X[(size_t)(m0 + lrow) * HIDDIM + kt + lk0];
        float4 wv = *(const float4*)&W[(size_t)(n0 + lrow) * HIDDIM + kt + lk0];
        __syncthreads();
        Xs[lk0 + 0][lrow] = xv.x; Xs[lk0 + 1][lrow] = xv.y;
        Xs[lk0 + 2][lrow] = xv.z; Xs[lk0 + 3][lrow] = xv.w;
        Ws[lk0 + 0][lrow] = wv.x; Ws[lk0 + 1][lrow] = wv.y;
        Ws[lk0 + 2][lrow] = wv.z; Ws[lk0 + 3][lrow] = wv.w;
        __syncthreads();
#pragma unroll
        for (int kk = 0; kk < 16; ++kk) {
            float4 a = *(const float4*)&Xs[kk][ty << 2];
            float4 b = *(const float4*)&Ws[kk][tx << 2];
            float av[4] = {a.x, a.y, a.z, a.w};
            float bv[4] = {b.x, b.y, b.z, b.w};
#pragma unroll
            for (int i = 0; i < 4; ++i)
#pragma unroll
                for (int j = 0; j < 4; ++j) acc[i][j] += av[i] * bv[j];
        }
    }

#pragma unroll
    for (int i = 0; i < 4; ++i) {
        const int m  = m0 + (ty << 2) + i;
        const int bb = m >> 11;
        const int ss = m & 2047;
#pragma unroll
        for (int j = 0; j < 4; ++j) {
            const int n = n0 + (tx << 2) + j;
            const float v = (acc[i][j] + bias[n]) * scale;
            size_t idx;
            if (mode == 0) {
                idx = (size_t)m * HIDDIM + n;
            } else {
                const int h = n >> 6, d = n & 63;
                if (mode == 1)
                    idx = ((size_t)(bb * NHEAD + h) * S_LEN + ss) * DHEAD + d;
                else
                    idx = ((size_t)(bb * NHEAD + h) * DHEAD + d) * S_LEN + ss;
            }
            out[idx] = v;
        }
    }
}

// ---------------------------------------------------------------------------
// Fused entmax-1.33 attention.
// Grid 4096 blocks x 1024 threads (16 waves). Block owns (bh, 16 q-rows).
// Phase A (k-sliced, K read ONCE per block): wave w owns k-slice
//   [128w,128w+128), lane tc owns k-pair, all 16 rows in regs -> fp32 LDS.
// Phase B: wave w owns row w, lane holds 32 elems in regs. BISECTION
//   (round-6-validated update rule: f_lo >= 0 always so test is sum >= 1),
//   18 iters (tau err <= 0.92*2^-18 = 3.5e-6), each pass 1 trans/element
//   via the u^3*poly trick. Tree partial sums for ILP.
// Phase D: wave w owns d in {4w..4w+3}; transposed V read once per block;
//   4 independent accumulators.
// XCD swizzle: XCD x gets bh in [4x,4x+4) so K+V (1 MB) stays L2-resident.
// ---------------------------------------------------------------------------
__global__ __launch_bounds__(1024) void attn_entmax(
    const float* __restrict__ Q,   // [32][2048][64], pre-scaled by (a-1)/sqrt(DH)
    const float* __restrict__ Kt,  // [32][64][2048]
    const float* __restrict__ Vt,  // [32][64][2048]
    float* __restrict__ CTX,       // [8192][512]
    float zc, float dm0)
{
    __shared__ float S[16][2052];   // fp32 scores -> probs (131.3 KB)
    __shared__ float Qs[16][64];
    __shared__ float rowsum[16];

    const int bid = blockIdx.x;
    const int bh  = ((bid & 7) << 2) + (bid >> 10);   // XCD-local bh
    const int q0  = ((bid >> 3) & 127) << 4;
    const int t   = threadIdx.x;
    const int w   = t >> 6;     // wave 0..15
    const int tc  = t & 63;

    if (t < 256) {   // load 16x64 Q tile
        const int r = t >> 4;
        const int d = (t & 15) << 2;
        *(float4*)&Qs[r][d] =
            *(const float4*)&Q[((size_t)bh * S_LEN + q0 + r) * DHEAD + d];
    }
    __syncthreads();

    // ---- Phase A: scores. wave w: k-slice; lane: k-pair, all 16 rows -----
    {
        const int kbase = (w << 7) + (tc << 1);
        float sc0[16], sc1[16];
#pragma unroll
        for (int r = 0; r < 16; ++r) { sc0[r] = 0.f; sc1[r] = 0.f; }

        const float* kp = Kt + (size_t)bh * DHEAD * S_LEN + kbase;
        for (int d = 0; d < DHEAD; d += 2) {
            const float2 ka = *(const float2*)(kp);
            const float2 kb = *(const float2*)(kp + S_LEN);
            kp += 2 * S_LEN;
#pragma unroll
            for (int r = 0; r < 16; ++r) {
                const float2 q = *(const float2*)&Qs[r][d];   // wave-uniform broadcast
                sc0[r] += q.x * ka.x + q.y * kb.x;
                sc1[r] += q.x * ka.y + q.y * kb.y;
            }
        }
#pragma unroll
        for (int r = 0; r < 16; ++r)
            *(float2*)&S[r][kbase] = make_float2(sc0[r], sc1[r]);
    }
    __syncthreads();

    // ---- Phase B: per-wave bisection. wave w owns row w. -----------------
    {
        float sc[32];
#pragma unroll
        for (int j = 0; j < 8; ++j) {
            float4 v = *(const float4*)&S[w][(j << 8) + (tc << 2)];
            sc[4 * j + 0] = v.x; sc[4 * j + 1] = v.y;
            sc[4 * j + 2] = v.z; sc[4 * j + 3] = v.w;
        }

        // row max -> tau = max - 1
        float m = fmaxf(sc[0], sc[1]);
#pragma unroll
        for (int j = 2; j < 32; ++j) m = fmaxf(m, sc[j]);
#pragma unroll
        for (int o = 1; o < 64; o <<= 1) m = fmaxf(m, __shfl_xor(m, o, 64));
        float tau = m - 1.0f;

        // f_lo = sum(clip(Xa-(max-1))^inv)-1 >= 0 always (max elem alone = 1),
        // so reference's f_m*f_lo>=0 test == (sum_m >= 1).
        float dm = dm0;
        for (int it = 0; it < 18; ++it) {
            dm *= 0.5f;
            const float tm = tau + dm;
            float s[4] = {0.f, 0.f, 0.f, 0.f};
#pragma unroll
            for (int j = 0; j < 32; ++j)
                s[j & 3] += upow(fmaxf(sc[j] - tm, 1e-30f), zc);
            float st = (s[0] + s[1]) + (s[2] + s[3]);
#pragma unroll
            for (int o = 1; o < 64; o <<= 1) st += __shfl_xor(st, o, 64);
            if (st >= 1.0f) tau = tm;
        }

        // final probs -> LDS, row sum
        float s[4] = {0.f, 0.f, 0.f, 0.f};
#pragma unroll
        for (int j = 0; j < 8; ++j) {
            float4 p4;
#pragma unroll
            for (int c = 0; c < 4; ++c) {
                const float p = upow(fmaxf(sc[4 * j + c] - tau, 1e-30f), zc);
                ((float*)&p4)[c] = p;
                s[c] += p;
            }
            *(float4*)&S[w][(j << 8) + (tc << 2)] = p4;
        }
        float st = (s[0] + s[1]) + (s[2] + s[3]);
#pragma unroll
        for (int o = 1; o < 64; o <<= 1) st += __shfl_xor(st, o, 64);
        if (tc == 0) rowsum[w] = st;
    }
    __syncthreads();

    // ---- Phase D: PV. wave w owns d in {4w..4w+3}; lane: (row, d) --------
    const int row = tc >> 2;
    const int d   = (w << 2) + (tc & 3);
    const float* vp = Vt + ((size_t)bh * DHEAD + d) * S_LEN;
    float a0 = 0.f, a1 = 0.f, a2 = 0.f, a3 = 0.f;
    for (int k = 0; k < S_LEN; k += 16) {
#pragma unroll
        for (int c = 0; c < 4; ++c) {
            float4 p4 = *(const float4*)&S[row][k + 4 * c];
            float4 v  = *(const float4*)&vp[k + 4 * c];
            const float e = (p4.x * v.x + p4.y * v.y) + (p4.z * v.z + p4.w * v.w);
            if (c == 0) a0 += e; else if (c == 1) a1 += e;
            else if (c == 2) a2 += e; else a3 += e;
        }
    }
    float acc = ((a0 + a1) + (a2 + a3)) * fast_rcp(rowsum[row]);
    const int b = bh >> 3, h = bh & 7;
    CTX[((size_t)b * S_LEN + q0 + row) * HIDDIM + (h << 6) + d] = acc;
}

// ---------------------------------------------------------------------------
extern "C" void kernel_launch(void* const* d_in, const int* in_sizes, int n_in,
                              void* d_out, int out_size, void* d_ws, size_t ws_size,
                              hipStream_t stream)
{
    const float* hs = (const float*)d_in[0];
    const float* Wq = (const float*)d_in[1];
    const float* bq = (const float*)d_in[2];
    const float* Wk = (const float*)d_in[3];
    const float* bk = (const float*)d_in[4];
    const float* Wv = (const float*)d_in[5];
    const float* bv = (const float*)d_in[6];
    const float* Wo = (const float*)d_in[7];
    const float* bo = (const float*)d_in[8];
    float* out = (float*)d_out;

    const size_t per = (size_t)NBH * S_LEN * DHEAD;
    float* Qb  = (float*)d_ws;
    float* Ktb = Qb  + per;
    float* Vtb = Ktb + per;
    float* CTX = Vtb + per;

    const double am1d  = 1.33 - 1.0;                    // alpha - 1
    const float qscale = (float)(am1d / 8.0);           // fold (a-1)/sqrt(DH) into Q
    const float zc     = (float)((1.0 / am1d - 3.0) * M_LN2); // (pinv-3)*ln2
    const float dm0    = (float)(1.0 - exp2(-11.0 * am1d));   // 1-(1/2048)^(a-1)

    dim3 gp(MTOT / 64, HIDDIM / 64);
    gemm_xwt<<<gp, 256, 0, stream>>>(hs, Wq, bq, Qb,  1, qscale);
    gemm_xwt<<<gp, 256, 0, stream>>>(hs, Wk, bk, Ktb, 2, 1.0f);
    gemm_xwt<<<gp, 256, 0, stream>>>(hs, Wv, bv, Vtb, 2, 1.0f);
    attn_entmax<<<dim3(NBH * (S_LEN / 16)), 1024, 0, stream>>>(Qb, Ktb, Vtb, CTX, zc, dm0);
    gemm_xwt<<<gp, 256, 0, stream>>>(CTX, Wo, bo, out, 0, 1.0f);
}